// Round 8
// baseline (436.158 us; speedup 1.0000x reference)
//
#include <hip/hip_runtime.h>

#define HW_N 65536
#define CC 192
#define NCHUNKS 256

typedef __attribute__((ext_vector_type(8))) short short8v;
typedef __attribute__((ext_vector_type(4))) short short4v;
typedef __attribute__((ext_vector_type(4))) float f32x4;
typedef __attribute__((ext_vector_type(4))) int int4v;

__device__ __forceinline__ float bf2f(unsigned short u) {
  union { unsigned int i; float f; } v; v.i = ((unsigned int)u) << 16; return v.f;
}
__device__ __forceinline__ unsigned short f2bf(float f) {
  union { float f; unsigned int i; } v; v.f = f;
  unsigned int r = v.i + 0x7fffu + ((v.i >> 16) & 1u);
  return (unsigned short)(r >> 16);
}

// ---------------- weight preconversion f32 -> bf16 ----------------
__global__ __launch_bounds__(256) void cvt_w(
    const float* __restrict__ qw, const float* __restrict__ kvw,
    unsigned short* __restrict__ Wq, unsigned short* __restrict__ Wkv) {
  const int i = (blockIdx.x * 256 + threadIdx.x) * 8;
  const float* src; unsigned short* dst; int off;
  if (i < 36864) { src = qw; dst = Wq; off = i; }
  else { src = kvw; dst = Wkv; off = i - 36864; }
  unsigned short tmp[8];
#pragma unroll
  for (int j = 0; j < 8; ++j) tmp[j] = f2bf(src[off + j]);
  *(short8v*)(dst + off) = *(short8v*)tmp;
}

// ---------------- conv1x1 GEMM from NCHW input, small-tile high-occupancy ----
// out[b][m][n] = sum_k W[m][k] * X[b][k][n] + bias[m]
// 256 thr = 4 waves; tile 192m x 64n; wave = 48m x 64n (3x4 frags).
// LDS 25.6 KB -> ~6 blocks/CU so load bursts from many blocks interleave.
template <int INF32, int OUTF32, int PERB>
__global__ __launch_bounds__(256, 6) void conv_gemm(
    const void* __restrict__ X_, const unsigned short* __restrict__ W,
    const float* __restrict__ bias, void* __restrict__ out_,
    int Mtot, int msplit) {
  __shared__ __align__(16) unsigned char smem[25600];
  typedef unsigned short row200[200];
  typedef unsigned short row76[76];
  row200* Bt = (row200*)smem;   // [64][200] bf16, [n][k-octets swizzled]
  row76* Rp = (row76*)smem;     // [96][76] bf16 (aliased; bf16-out epilogue)
  const int d = blockIdx.x;
  int mt, nt;
  if (msplit == 2) { mt = (d >> 3) & 1; nt = (d & 7) | ((d >> 4) << 3); }
  else { mt = 0; nt = d; }
  const int m0 = mt * 192, n0 = nt * 64;
  const int b = blockIdx.z;
  const int t = threadIdx.x;
  const int lane = t & 63, wv = t >> 6;
  const int l15 = lane & 15, lg = lane >> 4;
  const int wm = wv;                 // 4 waves cover 4 x 48 m-rows
  const int mrow = m0 + wm * 48;
  const size_t xbase = (size_t)b * CC * (size_t)HW_N + n0;
  const unsigned short* Wb = W + (PERB ? (size_t)b * Mtot * CC : 0);

  // ---- one-shot staging: 24 k-octets x 16 n-quads = 384 tasks ----
  for (int task = t; task < 384; task += 256) {
    const int kp = task >> 4, nq = task & 15;
    unsigned int p[8][2];
    if (INF32) {
      const float* Xf = (const float*)X_;
#pragma unroll
      for (int j = 0; j < 8; ++j) {
        f32x4 v = *(const f32x4*)(Xf + xbase + (size_t)(kp * 8 + j) * HW_N + nq * 4);
        p[j][0] = (unsigned int)f2bf(v[0]) | ((unsigned int)f2bf(v[1]) << 16);
        p[j][1] = (unsigned int)f2bf(v[2]) | ((unsigned int)f2bf(v[3]) << 16);
      }
    } else {
      const unsigned short* Xh = (const unsigned short*)X_;
#pragma unroll
      for (int j = 0; j < 8; ++j) {
        short4v v = *(const short4v*)(Xh + xbase + (size_t)(kp * 8 + j) * HW_N + nq * 4);
        p[j][0] = (unsigned int)(unsigned short)v[0] | ((unsigned int)(unsigned short)v[1] << 16);
        p[j][1] = (unsigned int)(unsigned short)v[2] | ((unsigned int)(unsigned short)v[3] << 16);
      }
    }
    const int kpx = kp ^ (nq & 7);  // octet swizzle
#pragma unroll
    for (int nn = 0; nn < 4; ++nn) {
      unsigned int q4[4];
#pragma unroll
      for (int wi = 0; wi < 4; ++wi) {
        const unsigned int lo = (p[2 * wi][nn >> 1] >> ((nn & 1) * 16)) & 0xffffu;
        const unsigned int hi = (p[2 * wi + 1][nn >> 1] >> ((nn & 1) * 16)) & 0xffffu;
        q4[wi] = lo | (hi << 16);
      }
      *(int4v*)&Bt[nq * 4 + nn][kpx * 8] = *(int4v*)q4;
    }
  }
  __syncthreads();

  // ---- MFMA loop ----
  f32x4 acc[3][4] = {};
#pragma unroll
  for (int kc = 0; kc < 6; ++kc) {
    const int k0 = kc * 32 + lg * 8;
    short8v af[3], bfr[4];
#pragma unroll
    for (int fr = 0; fr < 3; ++fr)
      af[fr] = *(const short8v*)(Wb + (size_t)(mrow + fr * 16 + l15) * CC + k0);
#pragma unroll
    for (int fc = 0; fc < 4; ++fc) {
      const int row = fc * 16 + l15;
      const int oct = (kc * 4 + lg) ^ ((row >> 2) & 7);
      bfr[fc] = *(const short8v*)&Bt[row][oct * 8];
    }
#pragma unroll
    for (int fr = 0; fr < 3; ++fr)
#pragma unroll
      for (int fc = 0; fc < 4; ++fc)
        acc[fr][fc] = __builtin_amdgcn_mfma_f32_16x16x32_bf16(af[fr], bfr[fc], acc[fr][fc], 0, 0, 0);
  }

  const size_t obase = (size_t)b * Mtot * (size_t)HW_N;
  if (OUTF32) {
    // direct f32 stores from acc
    float* outf = (float*)out_;
#pragma unroll
    for (int fr = 0; fr < 3; ++fr) {
      const int rbase = mrow + fr * 16 + lg * 4;
#pragma unroll
      for (int r = 0; r < 4; ++r) {
        const float bb = bias[rbase + r];
        const size_t ro = obase + (size_t)(rbase + r) * HW_N + n0;
#pragma unroll
        for (int fc = 0; fc < 4; ++fc)
          outf[ro + fc * 16 + l15] = acc[fr][fc][r] + bb;
      }
    }
    return;
  }
  __syncthreads();  // Bt dead; Rp may alias

#pragma unroll
  for (int half = 0; half < 2; ++half) {
    if ((wm >> 1) == half) {
      const int mbase = (wm & 1) * 48;
#pragma unroll
      for (int fr = 0; fr < 3; ++fr) {
#pragma unroll
        for (int r = 0; r < 4; ++r) {
          const int mloc = mbase + fr * 16 + lg * 4 + r;
          const float bb = bias[m0 + half * 96 + mloc];
#pragma unroll
          for (int fc = 0; fc < 4; ++fc)
            Rp[mloc][fc * 16 + l15] = f2bf(acc[fr][fc][r] + bb);
        }
      }
    }
    __syncthreads();
#pragma unroll
    for (int s = 0; s < 3; ++s) {
      const int idx = s * 256 + t;           // 768 tasks: 96 rows x 8 col-octets
      const int m = idx >> 3, no = (idx & 7) * 8;
      short4v v0 = *(short4v*)&Rp[m][no];
      short4v v1 = *(short4v*)&Rp[m][no + 4];
      union { short8v v; short4v h[2]; } o;
      o.h[0] = v0; o.h[1] = v1;
      const size_t oo = obase + (size_t)(m0 + half * 96 + m) * HW_N + n0 + no;
      *(short8v*)((unsigned short*)out_ + oo) = o.v;
    }
    __syncthreads();
  }
}

// ---------------- depthwise 3x3, pad=1; 2 output rows per thread ----------------
__global__ __launch_bounds__(256) void dwconv3x3_all(
    const unsigned short* __restrict__ QC, const unsigned short* __restrict__ KVC,
    const float* __restrict__ q_dw_w, const float* __restrict__ q_dw_b,
    const float* __restrict__ kv_dw_w, const float* __restrict__ kv_dw_b,
    unsigned short* __restrict__ Qb, unsigned short* __restrict__ Kb,
    unsigned short* __restrict__ Vb) {
  const int t = threadIdx.x;
  const int wc = (t & 31) * 8;
  const int h0 = blockIdx.x * 16 + (t >> 5) * 2;
  const int y = blockIdx.y, b = blockIdx.z;
  const unsigned short* in; const float* w; float bv; unsigned short* out;
  if (y < 192) {
    in = QC + ((size_t)b * 192 + y) * (size_t)HW_N;
    w = q_dw_w + y * 9; bv = q_dw_b[y];
    out = Qb + ((size_t)b * 192 + y) * (size_t)HW_N;
  } else if (y < 384) {
    const int c = y - 192;
    in = KVC + ((size_t)b * 384 + c) * (size_t)HW_N;
    w = kv_dw_w + c * 9; bv = kv_dw_b[c];
    out = Kb + ((size_t)b * 192 + c) * (size_t)HW_N;
  } else {
    const int c = y - 384;
    in = KVC + ((size_t)b * 384 + 192 + c) * (size_t)HW_N;
    w = kv_dw_w + (192 + c) * 9; bv = kv_dw_b[192 + c];
    out = Vb + ((size_t)b * 192 + c) * (size_t)HW_N;
  }
  float wv9[9];
#pragma unroll
  for (int i = 0; i < 9; ++i) wv9[i] = w[i];
  float f[4][10];
#pragma unroll
  for (int ky = 0; ky < 4; ++ky) {
    const int hh = h0 + ky - 1;
    if (hh < 0 || hh > 255) {
#pragma unroll
      for (int j = 0; j < 10; ++j) f[ky][j] = 0.f;
    } else {
      const unsigned short* row = in + hh * 256;
      short8v v = *(const short8v*)(row + wc);
      f[ky][0] = (wc > 0) ? bf2f(row[wc - 1]) : 0.f;
#pragma unroll
      for (int j = 0; j < 8; ++j) f[ky][1 + j] = bf2f((unsigned short)v[j]);
      f[ky][9] = (wc < 248) ? bf2f(row[wc + 8]) : 0.f;
    }
  }
#pragma unroll
  for (int rr = 0; rr < 2; ++rr) {
    union { short8v v; unsigned short u[8]; } o;
#pragma unroll
    for (int j = 0; j < 8; ++j) {
      float acc = bv;
#pragma unroll
      for (int ky = 0; ky < 3; ++ky)
#pragma unroll
        for (int kx = 0; kx < 3; ++kx)
          acc += wv9[ky * 3 + kx] * f[rr + ky][j + kx];
      o.u[j] = f2bf(acc);
    }
    *(short8v*)(out + (h0 + rr) * 256 + wc) = o.v;
  }
}

// ---------------- Gram partials: G[c][d] = sum_n Q[c,n]K[d,n]; + sumsq ----------------
__global__ __launch_bounds__(64) void gram_kernel(
    const unsigned short* __restrict__ Q, const unsigned short* __restrict__ K,
    float* __restrict__ Gp, float* __restrict__ nqp, float* __restrict__ nkp) {
  const int lane = threadIdx.x;
  const int l15 = lane & 15, lg = lane >> 4;
  const int chunk = blockIdx.x, h = blockIdx.y, b = blockIdx.z;
  const int bh = b * 6 + h;
  const size_t base = ((size_t)b * CC + h * 32) * (size_t)HW_N;
  f32x4 acc[2][2] = {};
  float sq[2] = {0.f, 0.f}, sk[2] = {0.f, 0.f};
  const int nst = chunk * 256 + lg * 8;
  for (int ks = 0; ks < 8; ++ks) {
    const int n = nst + ks * 32;
    short8v qa[2], kb[2];
#pragma unroll
    for (int fr = 0; fr < 2; ++fr) {
      qa[fr] = *(const short8v*)(Q + base + (size_t)(fr * 16 + l15) * HW_N + n);
      kb[fr] = *(const short8v*)(K + base + (size_t)(fr * 16 + l15) * HW_N + n);
    }
#pragma unroll
    for (int fr = 0; fr < 2; ++fr)
#pragma unroll
      for (int j = 0; j < 8; ++j) {
        float a = bf2f((unsigned short)qa[fr][j]); sq[fr] += a * a;
        float c2 = bf2f((unsigned short)kb[fr][j]); sk[fr] += c2 * c2;
      }
#pragma unroll
    for (int fr = 0; fr < 2; ++fr)
#pragma unroll
      for (int fc = 0; fc < 2; ++fc)
        acc[fr][fc] = __builtin_amdgcn_mfma_f32_16x16x32_bf16(qa[fr], kb[fc], acc[fr][fc], 0, 0, 0);
  }
  float* Gb = Gp + (size_t)(chunk * 12 + bh) * 1024;
#pragma unroll
  for (int fr = 0; fr < 2; ++fr)
#pragma unroll
    for (int fc = 0; fc < 2; ++fc)
#pragma unroll
      for (int r = 0; r < 4; ++r)
        Gb[(fr * 16 + lg * 4 + r) * 32 + fc * 16 + l15] = acc[fr][fc][r];
#pragma unroll
  for (int fr = 0; fr < 2; ++fr) {
    float v = sq[fr]; v += __shfl_down(v, 32); v += __shfl_down(v, 16);
    float u = sk[fr]; u += __shfl_down(u, 32); u += __shfl_down(u, 16);
    if (lane < 16) {
      nqp[(size_t)(chunk * 12 + bh) * 32 + fr * 16 + lane] = v;
      nkp[(size_t)(chunk * 12 + bh) * 32 + fr * 16 + lane] = u;
    }
  }
}

// ---------------- reduce partials ----------------
__global__ __launch_bounds__(256) void reduce_gram(
    const float* __restrict__ Gp, const float* __restrict__ nqp, const float* __restrict__ nkp,
    float* __restrict__ G, float* __restrict__ nq, float* __restrict__ nk) {
  const int i = blockIdx.x * 256 + threadIdx.x;
  if (i < 12 * 1024) {
    float s = 0.f;
    for (int ch = 0; ch < NCHUNKS; ++ch) s += Gp[(size_t)ch * 12288 + i];
    G[i] = s;
  } else if (i < 12 * 1024 + 384) {
    const int j = i - 12 * 1024;
    float s = 0.f;
    for (int ch = 0; ch < NCHUNKS; ++ch) s += nqp[(size_t)ch * 384 + j];
    nq[j] = s;
  } else if (i < 12 * 1024 + 768) {
    const int j = i - 12 * 1024 - 384;
    float s = 0.f;
    for (int ch = 0; ch < NCHUNKS; ++ch) s += nkp[(size_t)ch * 384 + j];
    nk[j] = s;
  }
}

// ---------------- softmax + fold proj: M[b] = proj_w @ blockdiag(attn) ----------------
__global__ __launch_bounds__(256) void attn_proj(
    const float* __restrict__ G, const float* __restrict__ nq, const float* __restrict__ nk,
    const float* __restrict__ temp, const float* __restrict__ proj_w,
    unsigned short* __restrict__ Mout) {
  const int h = blockIdx.x, b = blockIdx.y;
  const int bh = b * 6 + h;
  const int t = threadIdx.x;
  __shared__ float sc[32][33];
  __shared__ float nrmq[32], nrmk[32];
  if (t < 32) nrmq[t] = fmaxf(sqrtf(nq[bh * 32 + t]), 1e-12f);
  else if (t < 64) nrmk[t - 32] = fmaxf(sqrtf(nk[bh * 32 + t - 32]), 1e-12f);
  __syncthreads();
  const float tpr = temp[h];
  for (int i = t; i < 1024; i += 256) {
    const int c = i >> 5, d = i & 31;
    sc[c][d] = G[bh * 1024 + i] * tpr / (nrmq[c] * nrmk[d]);
  }
  __syncthreads();
  if (t < 32) {
    float mx = -1e30f;
    for (int d = 0; d < 32; ++d) mx = fmaxf(mx, sc[t][d]);
    float sum = 0.f;
    for (int d = 0; d < 32; ++d) { float e = __expf(sc[t][d] - mx); sc[t][d] = e; sum += e; }
    const float inv = 1.f / sum;
    for (int d = 0; d < 32; ++d) sc[t][d] *= inv;
  }
  __syncthreads();
  for (int i = t; i < 6144; i += 256) {
    const int co = i >> 5, d = i & 31;
    float acc = 0.f;
    for (int c = 0; c < 32; ++c) acc += proj_w[co * CC + h * 32 + c] * sc[c][d];
    Mout[((size_t)b * CC + co) * CC + h * 32 + d] = f2bf(acc);
  }
}

extern "C" void kernel_launch(void* const* d_in, const int* in_sizes, int n_in,
                              void* d_out, int out_size, void* d_ws, size_t ws_size,
                              hipStream_t stream) {
  const float* fg = (const float*)d_in[0];
  const float* fo = (const float*)d_in[1];
  const float* q_w = (const float*)d_in[2];
  const float* q_b = (const float*)d_in[3];
  const float* kv_w = (const float*)d_in[4];
  const float* kv_b = (const float*)d_in[5];
  const float* q_dw_w = (const float*)d_in[6];
  const float* q_dw_b = (const float*)d_in[7];
  const float* kv_dw_w = (const float*)d_in[8];
  const float* kv_dw_b = (const float*)d_in[9];
  const float* proj_w = (const float*)d_in[10];
  const float* proj_b = (const float*)d_in[11];
  const float* temp = (const float*)d_in[12];

  char* ws = (char*)d_ws;
  unsigned short* QC  = (unsigned short*)(ws + 0);            // [b][192][n]
  unsigned short* KVC = (unsigned short*)(ws + 50331648);     // [b][384][n]
  unsigned short* Qb  = (unsigned short*)(ws + 150994944);    // dw(QC)
  unsigned short* Kb  = (unsigned short*)(ws + 0);            // over QC (dispatch-distance ordered)
  unsigned short* Vb  = (unsigned short*)(ws + 50331648);     // over KVC K-half (same)
  float* Gp  = (float*)(ws + 100663296);                      // [256][12][1024]
  float* nqp = (float*)(ws + 113246208);                      // [256][12][32]
  float* nkp = (float*)(ws + 113639424);
  float* G   = (float*)(ws + 208011264);                      // [12][1024]
  float* nqv = (float*)(ws + 208060416);
  float* nkv = (float*)(ws + 208061952);
  unsigned short* Mw  = (unsigned short*)(ws + 208063488);    // [2][192][192]
  unsigned short* Wq  = (unsigned short*)(ws + 208210944);    // [192][192]
  unsigned short* Wkv = (unsigned short*)(ws + 208284672);    // [384][192]

  cvt_w<<<dim3(54), dim3(256), 0, stream>>>(q_w, kv_w, Wq, Wkv);
  conv_gemm<1, 0, 0><<<dim3(1024, 1, 2), dim3(256), 0, stream>>>(
      (const void*)fg, Wq, q_b, (void*)QC, 192, 1);
  conv_gemm<1, 0, 0><<<dim3(2048, 1, 2), dim3(256), 0, stream>>>(
      (const void*)fo, Wkv, kv_b, (void*)KVC, 384, 2);
  dwconv3x3_all<<<dim3(16, 576, 2), dim3(256), 0, stream>>>(
      QC, KVC, q_dw_w, q_dw_b, kv_dw_w, kv_dw_b, Qb, Kb, Vb);
  gram_kernel<<<dim3(NCHUNKS, 6, 2), dim3(64), 0, stream>>>(Qb, Kb, Gp, nqp, nkp);
  reduce_gram<<<dim3(51), dim3(256), 0, stream>>>(Gp, nqp, nkp, G, nqv, nkv);
  attn_proj<<<dim3(6, 2), dim3(256), 0, stream>>>(G, nqv, nkv, temp, proj_w, Mw);
  conv_gemm<0, 1, 1><<<dim3(1024, 1, 2), dim3(256), 0, stream>>>(
      (const void*)Vb, Mw, proj_b, d_out, 192, 1);
}

// Round 10
// 390.376 us; speedup vs baseline: 1.1173x; 1.1173x over previous
//
#include <hip/hip_runtime.h>

#define HW_N 65536
#define CC 192
#define NCHUNKS 256

typedef __attribute__((ext_vector_type(8))) short short8v;
typedef __attribute__((ext_vector_type(4))) short short4v;
typedef __attribute__((ext_vector_type(4))) float f32x4;
typedef __attribute__((ext_vector_type(4))) int int4v;

__device__ __forceinline__ float bf2f(unsigned short u) {
  union { unsigned int i; float f; } v; v.i = ((unsigned int)u) << 16; return v.f;
}
__device__ __forceinline__ unsigned short f2bf(float f) {
  union { float f; unsigned int i; } v; v.f = f;
  unsigned int r = v.i + 0x7fffu + ((v.i >> 16) & 1u);
  return (unsigned short)(r >> 16);
}

// ---------------- weight preconversion f32 -> bf16 ----------------
__global__ __launch_bounds__(256) void cvt_w(
    const float* __restrict__ qw, const float* __restrict__ kvw,
    unsigned short* __restrict__ Wq, unsigned short* __restrict__ Wkv) {
  const int i = (blockIdx.x * 256 + threadIdx.x) * 8;
  const float* src; unsigned short* dst; int off;
  if (i < 36864) { src = qw; dst = Wq; off = i; }
  else { src = kvw; dst = Wkv; off = i - 36864; }
  unsigned short tmp[8];
#pragma unroll
  for (int j = 0; j < 8; ++j) tmp[j] = f2bf(src[off + j]);
  *(short8v*)(dst + off) = *(short8v*)tmp;
}

// ---------------- conv1x1 GEMM from NCHW input (r7 structure) ----------------
template <int INF32, int OUTF32, int PERB>
__global__ __launch_bounds__(512) void conv_gemm(
    const void* __restrict__ X_, const unsigned short* __restrict__ W,
    const float* __restrict__ bias, void* __restrict__ out_,
    int Mtot, int msplit) {
  __shared__ __align__(16) unsigned char smem[51200];
  typedef unsigned short row200[200];
  typedef unsigned short row152[152];
  row200* Bt = (row200*)smem;   // [128][200] bf16, [n][k-octets swizzled]
  row152* Rp = (row152*)smem;   // [96][152] bf16 (aliased; bf16-out epilogue)
  const int d = blockIdx.x;
  int mt, nt;
  if (msplit == 2) { mt = (d >> 3) & 1; nt = (d & 7) | ((d >> 4) << 3); }
  else { mt = 0; nt = d; }
  const int m0 = mt * 192, n0 = nt * 128;
  const int b = blockIdx.z;
  const int t = threadIdx.x;
  const int lane = t & 63, wv = t >> 6;
  const int l15 = lane & 15, lg = lane >> 4;
  const int wm = wv & 3, wn = wv >> 2;
  const int mrow = m0 + wm * 48;
  const int nw = wn * 64;
  const size_t xbase = (size_t)b * CC * (size_t)HW_N + n0;
  const unsigned short* Wb = W + (PERB ? (size_t)b * Mtot * CC : 0);

  // ---- one-shot staging: 24 k-octets x 32 n-quads = 768 tasks ----
  for (int task = t; task < 768; task += 512) {
    const int kp = task >> 5, nq = task & 31;
    unsigned int p[8][2];
    if (INF32) {
      const float* Xf = (const float*)X_;
#pragma unroll
      for (int j = 0; j < 8; ++j) {
        f32x4 v = *(const f32x4*)(Xf + xbase + (size_t)(kp * 8 + j) * HW_N + nq * 4);
        p[j][0] = (unsigned int)f2bf(v[0]) | ((unsigned int)f2bf(v[1]) << 16);
        p[j][1] = (unsigned int)f2bf(v[2]) | ((unsigned int)f2bf(v[3]) << 16);
      }
    } else {
      const unsigned short* Xh = (const unsigned short*)X_;
#pragma unroll
      for (int j = 0; j < 8; ++j) {
        short4v v = *(const short4v*)(Xh + xbase + (size_t)(kp * 8 + j) * HW_N + nq * 4);
        p[j][0] = (unsigned int)(unsigned short)v[0] | ((unsigned int)(unsigned short)v[1] << 16);
        p[j][1] = (unsigned int)(unsigned short)v[2] | ((unsigned int)(unsigned short)v[3] << 16);
      }
    }
    const int kpx = kp ^ (nq & 7);  // octet swizzle
#pragma unroll
    for (int nn = 0; nn < 4; ++nn) {
      unsigned int q4[4];
#pragma unroll
      for (int wi = 0; wi < 4; ++wi) {
        const unsigned int lo = (p[2 * wi][nn >> 1] >> ((nn & 1) * 16)) & 0xffffu;
        const unsigned int hi = (p[2 * wi + 1][nn >> 1] >> ((nn & 1) * 16)) & 0xffffu;
        q4[wi] = lo | (hi << 16);
      }
      *(int4v*)&Bt[nq * 4 + nn][kpx * 8] = *(int4v*)q4;
    }
  }
  __syncthreads();

  // ---- MFMA loop ----
  f32x4 acc[3][4] = {};
#pragma unroll
  for (int kc = 0; kc < 6; ++kc) {
    const int k0 = kc * 32 + lg * 8;
    short8v af[3], bfr[4];
#pragma unroll
    for (int fr = 0; fr < 3; ++fr)
      af[fr] = *(const short8v*)(Wb + (size_t)(mrow + fr * 16 + l15) * CC + k0);
#pragma unroll
    for (int fc = 0; fc < 4; ++fc) {
      const int row = nw + fc * 16 + l15;
      const int oct = (kc * 4 + lg) ^ ((row >> 2) & 7);
      bfr[fc] = *(const short8v*)&Bt[row][oct * 8];
    }
#pragma unroll
    for (int fr = 0; fr < 3; ++fr)
#pragma unroll
      for (int fc = 0; fc < 4; ++fc)
        acc[fr][fc] = __builtin_amdgcn_mfma_f32_16x16x32_bf16(af[fr], bfr[fc], acc[fr][fc], 0, 0, 0);
  }

  const size_t obase = (size_t)b * Mtot * (size_t)HW_N;
  if (OUTF32) {
    float* outf = (float*)out_;
#pragma unroll
    for (int fr = 0; fr < 3; ++fr) {
      const int rbase = mrow + fr * 16 + lg * 4;
#pragma unroll
      for (int r = 0; r < 4; ++r) {
        const float bb = bias[rbase + r];
        const size_t ro = obase + (size_t)(rbase + r) * HW_N + n0 + nw;
#pragma unroll
        for (int fc = 0; fc < 4; ++fc)
          outf[ro + fc * 16 + l15] = acc[fr][fc][r] + bb;
      }
    }
    return;
  }
  __syncthreads();  // Bt dead; Rp may alias

#pragma unroll
  for (int half = 0; half < 2; ++half) {
    if ((wm >> 1) == half) {
      const int mbase = (wm & 1) * 48;
#pragma unroll
      for (int fr = 0; fr < 3; ++fr) {
#pragma unroll
        for (int r = 0; r < 4; ++r) {
          const int mloc = mbase + fr * 16 + lg * 4 + r;
          const float bb = bias[m0 + half * 96 + mloc];
#pragma unroll
          for (int fc = 0; fc < 4; ++fc)
            Rp[mloc][nw + fc * 16 + l15] = f2bf(acc[fr][fc][r] + bb);
        }
      }
    }
    __syncthreads();
#pragma unroll
    for (int s = 0; s < 3; ++s) {
      const int idx = s * 512 + t;
      const int m = idx >> 4, n8 = (idx & 15) * 8;
      short8v v = *(short8v*)&Rp[m][n8];
      const size_t oo = obase + (size_t)(m0 + half * 96 + m) * HW_N + n0 + n8;
      *(short8v*)((unsigned short*)out_ + oo) = v;
    }
    __syncthreads();
  }
}

// ---------------- depthwise 3x3 for V only ----------------
__global__ __launch_bounds__(256) void dwconv3x3_v(
    const unsigned short* __restrict__ KVC, const float* __restrict__ kv_dw_w,
    const float* __restrict__ kv_dw_b, unsigned short* __restrict__ Vb) {
  const int t = threadIdx.x;
  const int wc = (t & 31) * 8;
  const int h0 = blockIdx.x * 16 + (t >> 5) * 2;
  const int c = blockIdx.y, b = blockIdx.z;
  const unsigned short* in = KVC + ((size_t)b * 384 + 192 + c) * (size_t)HW_N;
  const float* w = kv_dw_w + (192 + c) * 9;
  const float bv = kv_dw_b[192 + c];
  unsigned short* out = Vb + ((size_t)b * CC + c) * (size_t)HW_N;
  float wv9[9];
#pragma unroll
  for (int i = 0; i < 9; ++i) wv9[i] = w[i];
  float f[4][10];
#pragma unroll
  for (int ky = 0; ky < 4; ++ky) {
    const int hh = h0 + ky - 1;
    if (hh < 0 || hh > 255) {
#pragma unroll
      for (int j = 0; j < 10; ++j) f[ky][j] = 0.f;
    } else {
      const unsigned short* row = in + hh * 256;
      short8v v = *(const short8v*)(row + wc);
      f[ky][0] = (wc > 0) ? bf2f(row[wc - 1]) : 0.f;
#pragma unroll
      for (int j = 0; j < 8; ++j) f[ky][1 + j] = bf2f((unsigned short)v[j]);
      f[ky][9] = (wc < 248) ? bf2f(row[wc + 8]) : 0.f;
    }
  }
#pragma unroll
  for (int rr = 0; rr < 2; ++rr) {
    union { short8v v; unsigned short u[8]; } o;
#pragma unroll
    for (int j = 0; j < 8; ++j) {
      float acc = bv;
#pragma unroll
      for (int ky = 0; ky < 3; ++ky)
#pragma unroll
        for (int kx = 0; kx < 3; ++kx)
          acc += wv9[ky * 3 + kx] * f[rr + ky][j + kx];
      o.u[j] = f2bf(acc);
    }
    *(short8v*)(out + (h0 + rr) * 256 + wc) = o.v;
  }
}

// ---------------- dwconv'd MFMA fragment: 8 px of one channel, one row ------
__device__ __forceinline__ short8v dwfrag(
    const unsigned short* __restrict__ chan, int r, int w0,
    const float* wv, float bv, float& ssq) {
  float fv[3][10];
#pragma unroll
  for (int ky = 0; ky < 3; ++ky) {
    const int rr = r + ky - 1;
    if (rr < 0 || rr > 255) {
#pragma unroll
      for (int j = 0; j < 10; ++j) fv[ky][j] = 0.f;
    } else {
      const unsigned short* rp = chan + rr * 256;
      short8v v = *(const short8v*)(rp + w0);
      fv[ky][0] = (w0 > 0) ? bf2f(rp[w0 - 1]) : 0.f;
#pragma unroll
      for (int j = 0; j < 8; ++j) fv[ky][1 + j] = bf2f((unsigned short)v[j]);
      fv[ky][9] = (w0 < 248) ? bf2f(rp[w0 + 8]) : 0.f;
    }
  }
  union { short8v v; unsigned short u[8]; } o;
#pragma unroll
  for (int j = 0; j < 8; ++j) {
    float a = bv;
#pragma unroll
    for (int ky = 0; ky < 3; ++ky)
#pragma unroll
      for (int kx = 0; kx < 3; ++kx)
        a += wv[ky * 3 + kx] * fv[ky][j + kx];
    const unsigned short us = f2bf(a);
    o.u[j] = us;
    const float q = bf2f(us);
    ssq += q * q;
  }
  return o.v;
}

// ---------------- fused dwconv + Gram partials ----------------
// chunk = image row r (256 px). Q = dw(QC), K = dw(KVC[0:192]).
__global__ __launch_bounds__(64) void gram_fused(
    const unsigned short* __restrict__ QC, const unsigned short* __restrict__ KVC,
    const float* __restrict__ q_dw_w, const float* __restrict__ q_dw_b,
    const float* __restrict__ kv_dw_w, const float* __restrict__ kv_dw_b,
    float* __restrict__ Gp, float* __restrict__ nqp, float* __restrict__ nkp) {
  const int lane = threadIdx.x;
  const int l15 = lane & 15, lg = lane >> 4;
  const int r = blockIdx.x, h = blockIdx.y, b = blockIdx.z;
  const int bh = b * 6 + h;
  int cc2[2];
  cc2[0] = h * 32 + l15; cc2[1] = h * 32 + 16 + l15;
  float wq[2][9], wk[2][9], bq[2], bk[2];
#pragma unroll
  for (int fr = 0; fr < 2; ++fr) {
#pragma unroll
    for (int i = 0; i < 9; ++i) {
      wq[fr][i] = q_dw_w[cc2[fr] * 9 + i];
      wk[fr][i] = kv_dw_w[cc2[fr] * 9 + i];
    }
    bq[fr] = q_dw_b[cc2[fr]];
    bk[fr] = kv_dw_b[cc2[fr]];
  }
  const unsigned short* qch[2];
  const unsigned short* kch[2];
#pragma unroll
  for (int fr = 0; fr < 2; ++fr) {
    qch[fr] = QC + ((size_t)b * CC + cc2[fr]) * (size_t)HW_N;
    kch[fr] = KVC + ((size_t)b * 384 + cc2[fr]) * (size_t)HW_N;
  }

  f32x4 acc[2][2] = {};
  float sq[2] = {0.f, 0.f}, sk[2] = {0.f, 0.f};
#pragma unroll
  for (int ks = 0; ks < 8; ++ks) {
    const int w0 = lg * 8 + ks * 32;
    short8v qa[2], kb[2];
#pragma unroll
    for (int fr = 0; fr < 2; ++fr) {
      qa[fr] = dwfrag(qch[fr], r, w0, wq[fr], bq[fr], sq[fr]);
      kb[fr] = dwfrag(kch[fr], r, w0, wk[fr], bk[fr], sk[fr]);
    }
#pragma unroll
    for (int fr = 0; fr < 2; ++fr)
#pragma unroll
      for (int fc = 0; fc < 2; ++fc)
        acc[fr][fc] = __builtin_amdgcn_mfma_f32_16x16x32_bf16(qa[fr], kb[fc], acc[fr][fc], 0, 0, 0);
  }
  float* Gb = Gp + (size_t)(r * 12 + bh) * 1024;
#pragma unroll
  for (int fr = 0; fr < 2; ++fr)
#pragma unroll
    for (int fc = 0; fc < 2; ++fc)
#pragma unroll
      for (int rr = 0; rr < 4; ++rr)
        Gb[(fr * 16 + lg * 4 + rr) * 32 + fc * 16 + l15] = acc[fr][fc][rr];
#pragma unroll
  for (int fr = 0; fr < 2; ++fr) {
    float v = sq[fr]; v += __shfl_down(v, 32); v += __shfl_down(v, 16);
    float u = sk[fr]; u += __shfl_down(u, 32); u += __shfl_down(u, 16);
    if (lane < 16) {
      nqp[(size_t)(r * 12 + bh) * 32 + fr * 16 + lane] = v;
      nkp[(size_t)(r * 12 + bh) * 32 + fr * 16 + lane] = u;
    }
  }
}

// ---------------- reduce partials ----------------
__global__ __launch_bounds__(256) void reduce_gram(
    const float* __restrict__ Gp, const float* __restrict__ nqp, const float* __restrict__ nkp,
    float* __restrict__ G, float* __restrict__ nq, float* __restrict__ nk) {
  const int i = blockIdx.x * 256 + threadIdx.x;
  if (i < 12 * 1024) {
    float s = 0.f;
    for (int ch = 0; ch < NCHUNKS; ++ch) s += Gp[(size_t)ch * 12288 + i];
    G[i] = s;
  } else if (i < 12 * 1024 + 384) {
    const int j = i - 12 * 1024;
    float s = 0.f;
    for (int ch = 0; ch < NCHUNKS; ++ch) s += nqp[(size_t)ch * 384 + j];
    nq[j] = s;
  } else if (i < 12 * 1024 + 768) {
    const int j = i - 12 * 1024 - 384;
    float s = 0.f;
    for (int ch = 0; ch < NCHUNKS; ++ch) s += nkp[(size_t)ch * 384 + j];
    nk[j] = s;
  }
}

// ---------------- softmax + fold proj: M[b] = proj_w @ blockdiag(attn) ----------------
__global__ __launch_bounds__(256) void attn_proj(
    const float* __restrict__ G, const float* __restrict__ nq, const float* __restrict__ nk,
    const float* __restrict__ temp, const float* __restrict__ proj_w,
    unsigned short* __restrict__ Mout) {
  const int h = blockIdx.x, b = blockIdx.y;
  const int bh = b * 6 + h;
  const int t = threadIdx.x;
  __shared__ float sc[32][33];
  __shared__ float nrmq[32], nrmk[32];
  if (t < 32) nrmq[t] = fmaxf(sqrtf(nq[bh * 32 + t]), 1e-12f);
  else if (t < 64) nrmk[t - 32] = fmaxf(sqrtf(nk[bh * 32 + t - 32]), 1e-12f);
  __syncthreads();
  const float tpr = temp[h];
  for (int i = t; i < 1024; i += 256) {
    const int c = i >> 5, d = i & 31;
    sc[c][d] = G[bh * 1024 + i] * tpr / (nrmq[c] * nrmk[d]);
  }
  __syncthreads();
  if (t < 32) {
    float mx = -1e30f;
    for (int d = 0; d < 32; ++d) mx = fmaxf(mx, sc[t][d]);
    float sum = 0.f;
    for (int d = 0; d < 32; ++d) { float e = __expf(sc[t][d] - mx); sc[t][d] = e; sum += e; }
    const float inv = 1.f / sum;
    for (int d = 0; d < 32; ++d) sc[t][d] *= inv;
  }
  __syncthreads();
  for (int i = t; i < 6144; i += 256) {
    const int co = i >> 5, d = i & 31;
    float acc = 0.f;
    for (int c = 0; c < 32; ++c) acc += proj_w[co * CC + h * 32 + c] * sc[c][d];
    Mout[((size_t)b * CC + co) * CC + h * 32 + d] = f2bf(acc);
  }
}

extern "C" void kernel_launch(void* const* d_in, const int* in_sizes, int n_in,
                              void* d_out, int out_size, void* d_ws, size_t ws_size,
                              hipStream_t stream) {
  const float* fg = (const float*)d_in[0];
  const float* fo = (const float*)d_in[1];
  const float* q_w = (const float*)d_in[2];
  const float* q_b = (const float*)d_in[3];
  const float* kv_w = (const float*)d_in[4];
  const float* kv_b = (const float*)d_in[5];
  const float* q_dw_w = (const float*)d_in[6];
  const float* q_dw_b = (const float*)d_in[7];
  const float* kv_dw_w = (const float*)d_in[8];
  const float* kv_dw_b = (const float*)d_in[9];
  const float* proj_w = (const float*)d_in[10];
  const float* proj_b = (const float*)d_in[11];
  const float* temp = (const float*)d_in[12];

  char* ws = (char*)d_ws;
  unsigned short* QC  = (unsigned short*)(ws + 0);            // [b][192][n]
  unsigned short* KVC = (unsigned short*)(ws + 50331648);     // [b][384][n]
  unsigned short* Vb  = (unsigned short*)(ws + 0);            // over dead QC (after gram_fused)
  float* Gp  = (float*)(ws + 150994944);                      // [256][12][1024]
  float* nqp = (float*)(ws + 163577856);                      // [256][12][32]
  float* nkp = (float*)(ws + 163971072);
  float* G   = (float*)(ws + 208011264);                      // [12][1024]
  float* nqv = (float*)(ws + 208060416);
  float* nkv = (float*)(ws + 208061952);
  unsigned short* Mw  = (unsigned short*)(ws + 208063488);    // [2][192][192]
  unsigned short* Wq  = (unsigned short*)(ws + 208210944);    // [192][192]
  unsigned short* Wkv = (unsigned short*)(ws + 208284672);    // [384][192]

  cvt_w<<<dim3(54), dim3(256), 0, stream>>>(q_w, kv_w, Wq, Wkv);
  conv_gemm<1, 0, 0><<<dim3(512, 1, 2), dim3(512), 0, stream>>>(
      (const void*)fg, Wq, q_b, (void*)QC, 192, 1);
  conv_gemm<1, 0, 0><<<dim3(1024, 1, 2), dim3(512), 0, stream>>>(
      (const void*)fo, Wkv, kv_b, (void*)KVC, 384, 2);
  gram_fused<<<dim3(256, 6, 2), dim3(64), 0, stream>>>(
      QC, KVC, q_dw_w, q_dw_b, kv_dw_w, kv_dw_b, Gp, nqp, nkp);
  dwconv3x3_v<<<dim3(16, 192, 2), dim3(256), 0, stream>>>(
      KVC, kv_dw_w, kv_dw_b, Vb);
  reduce_gram<<<dim3(51), dim3(256), 0, stream>>>(Gp, nqp, nkp, G, nqv, nkv);
  attn_proj<<<dim3(6, 2), dim3(256), 0, stream>>>(G, nqv, nkv, temp, proj_w, Mw);
  conv_gemm<0, 1, 1><<<dim3(512, 1, 2), dim3(512), 0, stream>>>(
      (const void*)Vb, Mw, proj_b, d_out, 192, 1);
}

// Round 11
// 265.285 us; speedup vs baseline: 1.6441x; 1.4715x over previous
//
#include <hip/hip_runtime.h>

#define HW_N 65536
#define CC 192
#define NCHUNKS 256

typedef __attribute__((ext_vector_type(8))) short short8v;
typedef __attribute__((ext_vector_type(4))) short short4v;
typedef __attribute__((ext_vector_type(4))) float f32x4;
typedef __attribute__((ext_vector_type(4))) int int4v;

__device__ __forceinline__ float bf2f(unsigned short u) {
  union { unsigned int i; float f; } v; v.i = ((unsigned int)u) << 16; return v.f;
}
__device__ __forceinline__ unsigned short f2bf(float f) {
  union { float f; unsigned int i; } v; v.f = f;
  unsigned int r = v.i + 0x7fffu + ((v.i >> 16) & 1u);
  return (unsigned short)(r >> 16);
}

// ---------------- weight preconversion f32 -> bf16 ----------------
__global__ __launch_bounds__(256) void cvt_w(
    const float* __restrict__ qw, const float* __restrict__ kvw,
    unsigned short* __restrict__ Wq, unsigned short* __restrict__ Wkv) {
  const int i = (blockIdx.x * 256 + threadIdx.x) * 8;
  const float* src; unsigned short* dst; int off;
  if (i < 36864) { src = qw; dst = Wq; off = i; }
  else { src = kvw; dst = Wkv; off = i - 36864; }
  unsigned short tmp[8];
#pragma unroll
  for (int j = 0; j < 8; ++j) tmp[j] = f2bf(src[off + j]);
  *(short8v*)(dst + off) = *(short8v*)tmp;
}

// ---------------- shared GEMM body (r7 structure, verified) ----------------
// out[b][m][n] = sum_k W[m][k] * X[b][k][n] + bias[m]; 512 thr, tile 192m x 128n.
template <int INF32, int OUTF32>
__device__ __forceinline__ void gemm_body(
    const void* __restrict__ X_, const unsigned short* __restrict__ W,
    const float* __restrict__ bias, void* __restrict__ out_,
    int Mtot, int m0, int n0, int b, int t, unsigned char* smem) {
  typedef unsigned short row200[200];
  typedef unsigned short row152[152];
  row200* Bt = (row200*)smem;   // [128][200] bf16, [n][k-octets swizzled]
  row152* Rp = (row152*)smem;   // [96][152] bf16 (aliased; bf16-out epilogue)
  const int lane = t & 63, wv = t >> 6;
  const int l15 = lane & 15, lg = lane >> 4;
  const int wm = wv & 3, wn = wv >> 2;
  const int mrow = m0 + wm * 48;
  const int nw = wn * 64;
  const size_t xbase = (size_t)b * CC * (size_t)HW_N + n0;

  // ---- one-shot staging: 24 k-octets x 32 n-quads = 768 tasks ----
  for (int task = t; task < 768; task += 512) {
    const int kp = task >> 5, nq = task & 31;
    unsigned int p[8][2];
    if (INF32) {
      const float* Xf = (const float*)X_;
#pragma unroll
      for (int j = 0; j < 8; ++j) {
        f32x4 v = *(const f32x4*)(Xf + xbase + (size_t)(kp * 8 + j) * HW_N + nq * 4);
        p[j][0] = (unsigned int)f2bf(v[0]) | ((unsigned int)f2bf(v[1]) << 16);
        p[j][1] = (unsigned int)f2bf(v[2]) | ((unsigned int)f2bf(v[3]) << 16);
      }
    } else {
      const unsigned short* Xh = (const unsigned short*)X_;
#pragma unroll
      for (int j = 0; j < 8; ++j) {
        short4v v = *(const short4v*)(Xh + xbase + (size_t)(kp * 8 + j) * HW_N + nq * 4);
        p[j][0] = (unsigned int)(unsigned short)v[0] | ((unsigned int)(unsigned short)v[1] << 16);
        p[j][1] = (unsigned int)(unsigned short)v[2] | ((unsigned int)(unsigned short)v[3] << 16);
      }
    }
    const int kpx = kp ^ (nq & 7);  // octet swizzle
#pragma unroll
    for (int nn = 0; nn < 4; ++nn) {
      unsigned int q4[4];
#pragma unroll
      for (int wi = 0; wi < 4; ++wi) {
        const unsigned int lo = (p[2 * wi][nn >> 1] >> ((nn & 1) * 16)) & 0xffffu;
        const unsigned int hi = (p[2 * wi + 1][nn >> 1] >> ((nn & 1) * 16)) & 0xffffu;
        q4[wi] = lo | (hi << 16);
      }
      *(int4v*)&Bt[nq * 4 + nn][kpx * 8] = *(int4v*)q4;
    }
  }
  __syncthreads();

  // ---- MFMA loop ----
  f32x4 acc[3][4] = {};
#pragma unroll
  for (int kc = 0; kc < 6; ++kc) {
    const int k0 = kc * 32 + lg * 8;
    short8v af[3], bfr[4];
#pragma unroll
    for (int fr = 0; fr < 3; ++fr)
      af[fr] = *(const short8v*)(W + (size_t)(mrow + fr * 16 + l15) * CC + k0);
#pragma unroll
    for (int fc = 0; fc < 4; ++fc) {
      const int row = nw + fc * 16 + l15;
      const int oct = (kc * 4 + lg) ^ ((row >> 2) & 7);
      bfr[fc] = *(const short8v*)&Bt[row][oct * 8];
    }
#pragma unroll
    for (int fr = 0; fr < 3; ++fr)
#pragma unroll
      for (int fc = 0; fc < 4; ++fc)
        acc[fr][fc] = __builtin_amdgcn_mfma_f32_16x16x32_bf16(af[fr], bfr[fc], acc[fr][fc], 0, 0, 0);
  }

  const size_t obase = (size_t)b * Mtot * (size_t)HW_N;
  if (OUTF32) {
    float* outf = (float*)out_;
#pragma unroll
    for (int fr = 0; fr < 3; ++fr) {
      const int rbase = mrow + fr * 16 + lg * 4;
#pragma unroll
      for (int r = 0; r < 4; ++r) {
        const float bb = bias[rbase + r];
        const size_t ro = obase + (size_t)(rbase + r) * HW_N + n0 + nw;
#pragma unroll
        for (int fc = 0; fc < 4; ++fc)
          outf[ro + fc * 16 + l15] = acc[fr][fc][r] + bb;
      }
    }
    return;
  }
  __syncthreads();  // Bt dead; Rp may alias

#pragma unroll
  for (int half = 0; half < 2; ++half) {
    if ((wm >> 1) == half) {
      const int mbase = (wm & 1) * 48;
#pragma unroll
      for (int fr = 0; fr < 3; ++fr) {
#pragma unroll
        for (int r = 0; r < 4; ++r) {
          const int mloc = mbase + fr * 16 + lg * 4 + r;
          const float bb = bias[m0 + half * 96 + mloc];
#pragma unroll
          for (int fc = 0; fc < 4; ++fc)
            Rp[mloc][nw + fc * 16 + l15] = f2bf(acc[fr][fc][r] + bb);
        }
      }
    }
    __syncthreads();
#pragma unroll
    for (int s = 0; s < 3; ++s) {
      const int idx = s * 512 + t;
      const int m = idx >> 4, n8 = (idx & 15) * 8;
      short8v v = *(short8v*)&Rp[m][n8];
      const size_t oo = obase + (size_t)(m0 + half * 96 + m) * HW_N + n0 + n8;
      *(short8v*)((unsigned short*)out_ + oo) = v;
    }
    __syncthreads();
  }
}

// ---------------- merged q + kv conv1x1 GEMM: one dispatch ----------------
// d < 512: q (nt=d, m0=0).  d >= 512: kv, dd=d-512, mt from bit3, paired nt.
__global__ __launch_bounds__(512) void conv_gemm_qkv(
    const float* __restrict__ fg, const float* __restrict__ fo,
    const unsigned short* __restrict__ Wq, const unsigned short* __restrict__ Wkv,
    const float* __restrict__ q_b, const float* __restrict__ kv_b,
    unsigned short* __restrict__ QC, unsigned short* __restrict__ KVC) {
  __shared__ __align__(16) unsigned char smem[51200];
  const int d = blockIdx.x;
  const int b = blockIdx.z;
  const int t = threadIdx.x;
  if (d < 512) {
    gemm_body<1, 0>((const void*)fg, Wq, q_b, (void*)QC, 192, 0, d * 128, b, t, smem);
  } else {
    const int dd = d - 512;
    const int mt = (dd >> 3) & 1;
    const int nt = (dd & 7) | ((dd >> 4) << 3);
    gemm_body<1, 0>((const void*)fo, Wkv, kv_b, (void*)KVC, 384, mt * 192, nt * 128, b, t, smem);
  }
}

// ---------------- final GEMM: M[b] @ V -> f32 out ----------------
__global__ __launch_bounds__(512) void conv_gemm_final(
    const unsigned short* __restrict__ Vb, const unsigned short* __restrict__ Mw,
    const float* __restrict__ proj_b, float* __restrict__ out) {
  __shared__ __align__(16) unsigned char smem[51200];
  const int b = blockIdx.z;
  gemm_body<0, 1>((const void*)Vb, Mw + (size_t)b * CC * CC, proj_b, (void*)out,
                  192, 0, blockIdx.x * 128, b, threadIdx.x, smem);
}

// ---------------- depthwise 3x3, pad=1; 2 output rows per thread ----------------
__global__ __launch_bounds__(256) void dwconv3x3_all(
    const unsigned short* __restrict__ QC, const unsigned short* __restrict__ KVC,
    const float* __restrict__ q_dw_w, const float* __restrict__ q_dw_b,
    const float* __restrict__ kv_dw_w, const float* __restrict__ kv_dw_b,
    unsigned short* __restrict__ Qb, unsigned short* __restrict__ Kb,
    unsigned short* __restrict__ Vb) {
  const int t = threadIdx.x;
  const int wc = (t & 31) * 8;
  const int h0 = blockIdx.x * 16 + (t >> 5) * 2;
  const int y = blockIdx.y, b = blockIdx.z;
  const unsigned short* in; const float* w; float bv; unsigned short* out;
  if (y < 192) {
    in = QC + ((size_t)b * 192 + y) * (size_t)HW_N;
    w = q_dw_w + y * 9; bv = q_dw_b[y];
    out = Qb + ((size_t)b * 192 + y) * (size_t)HW_N;
  } else if (y < 384) {
    const int c = y - 192;
    in = KVC + ((size_t)b * 384 + c) * (size_t)HW_N;
    w = kv_dw_w + c * 9; bv = kv_dw_b[c];
    out = Kb + ((size_t)b * 192 + c) * (size_t)HW_N;
  } else {
    const int c = y - 384;
    in = KVC + ((size_t)b * 384 + 192 + c) * (size_t)HW_N;
    w = kv_dw_w + (192 + c) * 9; bv = kv_dw_b[192 + c];
    out = Vb + ((size_t)b * 192 + c) * (size_t)HW_N;
  }
  float wv9[9];
#pragma unroll
  for (int i = 0; i < 9; ++i) wv9[i] = w[i];
  float f[4][10];
#pragma unroll
  for (int ky = 0; ky < 4; ++ky) {
    const int hh = h0 + ky - 1;
    if (hh < 0 || hh > 255) {
#pragma unroll
      for (int j = 0; j < 10; ++j) f[ky][j] = 0.f;
    } else {
      const unsigned short* row = in + hh * 256;
      short8v v = *(const short8v*)(row + wc);
      f[ky][0] = (wc > 0) ? bf2f(row[wc - 1]) : 0.f;
#pragma unroll
      for (int j = 0; j < 8; ++j) f[ky][1 + j] = bf2f((unsigned short)v[j]);
      f[ky][9] = (wc < 248) ? bf2f(row[wc + 8]) : 0.f;
    }
  }
#pragma unroll
  for (int rr = 0; rr < 2; ++rr) {
    union { short8v v; unsigned short u[8]; } o;
#pragma unroll
    for (int j = 0; j < 8; ++j) {
      float acc = bv;
#pragma unroll
      for (int ky = 0; ky < 3; ++ky)
#pragma unroll
        for (int kx = 0; kx < 3; ++kx)
          acc += wv9[ky * 3 + kx] * f[rr + ky][j + kx];
      o.u[j] = f2bf(acc);
    }
    *(short8v*)(out + (h0 + rr) * 256 + wc) = o.v;
  }
}

// ---------------- Gram partials: G[c][d] = sum_n Q[c,n]K[d,n]; + sumsq ----------------
__global__ __launch_bounds__(64) void gram_kernel(
    const unsigned short* __restrict__ Q, const unsigned short* __restrict__ K,
    float* __restrict__ Gp, float* __restrict__ nqp, float* __restrict__ nkp) {
  const int lane = threadIdx.x;
  const int l15 = lane & 15, lg = lane >> 4;
  const int chunk = blockIdx.x, h = blockIdx.y, b = blockIdx.z;
  const int bh = b * 6 + h;
  const size_t base = ((size_t)b * CC + h * 32) * (size_t)HW_N;
  f32x4 acc[2][2] = {};
  float sq[2] = {0.f, 0.f}, sk[2] = {0.f, 0.f};
  const int nst = chunk * 256 + lg * 8;
  for (int ks = 0; ks < 8; ++ks) {
    const int n = nst + ks * 32;
    short8v qa[2], kb[2];
#pragma unroll
    for (int fr = 0; fr < 2; ++fr) {
      qa[fr] = *(const short8v*)(Q + base + (size_t)(fr * 16 + l15) * HW_N + n);
      kb[fr] = *(const short8v*)(K + base + (size_t)(fr * 16 + l15) * HW_N + n);
    }
#pragma unroll
    for (int fr = 0; fr < 2; ++fr)
#pragma unroll
      for (int j = 0; j < 8; ++j) {
        float a = bf2f((unsigned short)qa[fr][j]); sq[fr] += a * a;
        float c2 = bf2f((unsigned short)kb[fr][j]); sk[fr] += c2 * c2;
      }
#pragma unroll
    for (int fr = 0; fr < 2; ++fr)
#pragma unroll
      for (int fc = 0; fc < 2; ++fc)
        acc[fr][fc] = __builtin_amdgcn_mfma_f32_16x16x32_bf16(qa[fr], kb[fc], acc[fr][fc], 0, 0, 0);
  }
  float* Gb = Gp + (size_t)(chunk * 12 + bh) * 1024;
#pragma unroll
  for (int fr = 0; fr < 2; ++fr)
#pragma unroll
    for (int fc = 0; fc < 2; ++fc)
#pragma unroll
      for (int r = 0; r < 4; ++r)
        Gb[(fr * 16 + lg * 4 + r) * 32 + fc * 16 + l15] = acc[fr][fc][r];
#pragma unroll
  for (int fr = 0; fr < 2; ++fr) {
    float v = sq[fr]; v += __shfl_down(v, 32); v += __shfl_down(v, 16);
    float u = sk[fr]; u += __shfl_down(u, 32); u += __shfl_down(u, 16);
    if (lane < 16) {
      nqp[(size_t)(chunk * 12 + bh) * 32 + fr * 16 + lane] = v;
      nkp[(size_t)(chunk * 12 + bh) * 32 + fr * 16 + lane] = u;
    }
  }
}

// ---------------- reduce partials ----------------
__global__ __launch_bounds__(256) void reduce_gram(
    const float* __restrict__ Gp, const float* __restrict__ nqp, const float* __restrict__ nkp,
    float* __restrict__ G, float* __restrict__ nq, float* __restrict__ nk) {
  const int i = blockIdx.x * 256 + threadIdx.x;
  if (i < 12 * 1024) {
    float s = 0.f;
    for (int ch = 0; ch < NCHUNKS; ++ch) s += Gp[(size_t)ch * 12288 + i];
    G[i] = s;
  } else if (i < 12 * 1024 + 384) {
    const int j = i - 12 * 1024;
    float s = 0.f;
    for (int ch = 0; ch < NCHUNKS; ++ch) s += nqp[(size_t)ch * 384 + j];
    nq[j] = s;
  } else if (i < 12 * 1024 + 768) {
    const int j = i - 12 * 1024 - 384;
    float s = 0.f;
    for (int ch = 0; ch < NCHUNKS; ++ch) s += nkp[(size_t)ch * 384 + j];
    nk[j] = s;
  }
}

// ---------------- softmax + fold proj: M[b] = proj_w @ blockdiag(attn) ----------------
__global__ __launch_bounds__(256) void attn_proj(
    const float* __restrict__ G, const float* __restrict__ nq, const float* __restrict__ nk,
    const float* __restrict__ temp, const float* __restrict__ proj_w,
    unsigned short* __restrict__ Mout) {
  const int h = blockIdx.x, b = blockIdx.y;
  const int bh = b * 6 + h;
  const int t = threadIdx.x;
  __shared__ float sc[32][33];
  __shared__ float nrmq[32], nrmk[32];
  if (t < 32) nrmq[t] = fmaxf(sqrtf(nq[bh * 32 + t]), 1e-12f);
  else if (t < 64) nrmk[t - 32] = fmaxf(sqrtf(nk[bh * 32 + t - 32]), 1e-12f);
  __syncthreads();
  const float tpr = temp[h];
  for (int i = t; i < 1024; i += 256) {
    const int c = i >> 5, d = i & 31;
    sc[c][d] = G[bh * 1024 + i] * tpr / (nrmq[c] * nrmk[d]);
  }
  __syncthreads();
  if (t < 32) {
    float mx = -1e30f;
    for (int d = 0; d < 32; ++d) mx = fmaxf(mx, sc[t][d]);
    float sum = 0.f;
    for (int d = 0; d < 32; ++d) { float e = __expf(sc[t][d] - mx); sc[t][d] = e; sum += e; }
    const float inv = 1.f / sum;
    for (int d = 0; d < 32; ++d) sc[t][d] *= inv;
  }
  __syncthreads();
  for (int i = t; i < 6144; i += 256) {
    const int co = i >> 5, d = i & 31;
    float acc = 0.f;
    for (int c = 0; c < 32; ++c) acc += proj_w[co * CC + h * 32 + c] * sc[c][d];
    Mout[((size_t)b * CC + co) * CC + h * 32 + d] = f2bf(acc);
  }
}

extern "C" void kernel_launch(void* const* d_in, const int* in_sizes, int n_in,
                              void* d_out, int out_size, void* d_ws, size_t ws_size,
                              hipStream_t stream) {
  const float* fg = (const float*)d_in[0];
  const float* fo = (const float*)d_in[1];
  const float* q_w = (const float*)d_in[2];
  const float* q_b = (const float*)d_in[3];
  const float* kv_w = (const float*)d_in[4];
  const float* kv_b = (const float*)d_in[5];
  const float* q_dw_w = (const float*)d_in[6];
  const float* q_dw_b = (const float*)d_in[7];
  const float* kv_dw_w = (const float*)d_in[8];
  const float* kv_dw_b = (const float*)d_in[9];
  const float* proj_w = (const float*)d_in[10];
  const float* proj_b = (const float*)d_in[11];
  const float* temp = (const float*)d_in[12];

  char* ws = (char*)d_ws;
  unsigned short* QC  = (unsigned short*)(ws + 0);            // [b][192][n]
  unsigned short* KVC = (unsigned short*)(ws + 50331648);     // [b][384][n]
  unsigned short* Qb  = (unsigned short*)(ws + 150994944);    // dw(QC)
  unsigned short* Kb  = (unsigned short*)(ws + 0);            // over QC (192-ch dispatch distance)
  unsigned short* Vb  = (unsigned short*)(ws + 50331648);     // over KVC K-half (same)
  float* Gp  = (float*)(ws + 100663296);                      // [256][12][1024]
  float* nqp = (float*)(ws + 113246208);                      // [256][12][32]
  float* nkp = (float*)(ws + 113639424);
  float* G   = (float*)(ws + 208011264);                      // [12][1024]
  float* nqv = (float*)(ws + 208060416);
  float* nkv = (float*)(ws + 208061952);
  unsigned short* Mw  = (unsigned short*)(ws + 208063488);    // [2][192][192]
  unsigned short* Wq  = (unsigned short*)(ws + 208210944);    // [192][192]
  unsigned short* Wkv = (unsigned short*)(ws + 208284672);    // [384][192]

  cvt_w<<<dim3(54), dim3(256), 0, stream>>>(q_w, kv_w, Wq, Wkv);
  conv_gemm_qkv<<<dim3(1536, 1, 2), dim3(512), 0, stream>>>(
      fg, fo, Wq, Wkv, q_b, kv_b, QC, KVC);
  dwconv3x3_all<<<dim3(16, 576, 2), dim3(256), 0, stream>>>(
      QC, KVC, q_dw_w, q_dw_b, kv_dw_w, kv_dw_b, Qb, Kb, Vb);
  gram_kernel<<<dim3(NCHUNKS, 6, 2), dim3(64), 0, stream>>>(Qb, Kb, Gp, nqp, nkp);
  reduce_gram<<<dim3(51), dim3(256), 0, stream>>>(Gp, nqp, nkp, G, nqv, nkv);
  attn_proj<<<dim3(6, 2), dim3(256), 0, stream>>>(G, nqv, nkv, temp, proj_w, Mw);
  conv_gemm_final<<<dim3(512, 1, 2), dim3(512), 0, stream>>>(Vb, Mw, proj_b, (float*)d_out);
}